// Round 6
// baseline (666.225 us; speedup 1.0000x reference)
//
#include <hip/hip_runtime.h>
#include <cstdint>
#include <cstddef>

#define DEV static __device__ __forceinline__

constexpr int Bn = 4, LQ = 1024, Dm = 1024, Hh = 16, FFd = 4096, DHd = 64, NR = 32;
constexpr int ROWS = Bn * LQ; // 4096

typedef __attribute__((ext_vector_type(8))) short v8s;
typedef __attribute__((ext_vector_type(4))) float v4f;

DEV float bf2f(ushort u) { union { uint32_t i; float f; } w; w.i = ((uint32_t)u) << 16; return w.f; }
DEV ushort f2bf(float f) {
  union { float f; uint32_t i; } w; w.f = f;
  uint32_t r = w.i + 0x7fffu + ((w.i >> 16) & 1u);
  return (ushort)(r >> 16);
}
DEV uint32_t asu(float f) { union { float f; uint32_t i; } w; w.f = f; return w.i; }

// ---------------- segmented f32 -> bf16 convert (one launch for all inputs) ----------------
struct CvtArgs {
  const float* src[14];
  ushort* dst[14];
  int cum[15]; // cumulative float4-task offsets
};
__global__ __launch_bounds__(256)
void k_cvt_all(CvtArgs a) {
  int t = blockIdx.x * 256 + threadIdx.x;
  if (t >= a.cum[14]) return;
  int seg = 0;
#pragma unroll
  for (int s = 1; s < 14; s++) if (t >= a.cum[s]) seg = s;
  int u = t - a.cum[seg];
  float4 v = *(const float4*)(a.src[seg] + (size_t)u * 4);
  ushort4 w; w.x = f2bf(v.x); w.y = f2bf(v.y); w.z = f2bf(v.z); w.w = f2bf(v.w);
  *(ushort4*)(a.dst[seg] + (size_t)u * 4) = w;
}

// ---------------- bias concat: bqkv1[3072], bkv2[2048] ----------------
__global__ __launch_bounds__(256)
void k_bias(const float* __restrict__ bq1, const float* __restrict__ bk1, const float* __restrict__ bv1,
            const float* __restrict__ bk2, const float* __restrict__ bv2,
            float* __restrict__ o1, float* __restrict__ o2) {
  int t = blockIdx.x * 256 + threadIdx.x;
  if (t < 3072) o1[t] = t < 1024 ? bq1[t] : (t < 2048 ? bk1[t - 1024] : bv1[t - 2048]);
  else if (t < 5120) { int u = t - 3072; o2[u] = u < 1024 ? bk2[u] : bv2[u - 1024]; }
}

// ---------------- ids -> u8 (natural layout) ----------------
__global__ __launch_bounds__(256)
void k_ids8(const int* __restrict__ i1, const int* __restrict__ i2,
            unsigned char* __restrict__ o1, unsigned char* __restrict__ o2) {
  int t = blockIdx.x * 256 + threadIdx.x;
  const int n = LQ * LQ / 4;
  if (t >= 2 * n) return;
  const int* ip = t < n ? i1 : i2;
  unsigned char* op = t < n ? o1 : o2;
  int u = t < n ? t : t - n;
  int q = u >> 8;
  int k4 = (u & 255) * 4;
  int4 v = *(const int4*)(ip + (size_t)q * LQ + k4);
  uchar4 pk; pk.x = (unsigned char)v.x; pk.y = (unsigned char)v.y;
  pk.z = (unsigned char)v.z; pk.w = (unsigned char)v.w;
  *(uchar4*)(op + (size_t)q * LQ + k4) = pk;
}

// ---------------- bf16 GEMM: C[M,N] = A[M,K] * Bw[N,K]^T + bias ----------------
// m97 staging + 1-D grid with XCD-slab swizzle (each XCD owns an interleaved
// tn slab -> B working set <= 1MB fits its L2; A sweeps hit L3) + paired
// bf16 epilogue stores. BM=128 (4-wave 64x64 tiles) or BM=64 (4-wave 64x32,
// doubles blocks for N=1024 problems). OUT: 1 = bf16, 2 = bf16 + relu.
template<int OUT, int BM>
__global__ __launch_bounds__(256)
void k_gemm(const ushort* __restrict__ A, const ushort* __restrict__ Bw,
            const float* __restrict__ bias, void* __restrict__ Cp,
            int M, int N, int K) {
  constexpr int BN = 128, BK = 32;
  constexpr int NI = 4, NJ = (BM == 128) ? 4 : 2;
  __shared__ __align__(16) ushort As[BM * BK];
  __shared__ __align__(16) ushort Bs[BN * BK];
  const int nN = N >> 7, k8 = nN >> 3;
  const int bid = blockIdx.x;
  const int xcd = bid & 7, sb = bid >> 3;
  const int tn = (xcd + ((sb % k8) << 3)) << 7;  // tn cycles fastest on each XCD
  const int tm = (sb / k8) * BM;
  const int tid = threadIdx.x;
  const int wave = tid >> 6, lane = tid & 63;
  const int wm = (BM == 128) ? (wave & 1) * 64 : 0;
  const int wn = (BM == 128) ? (wave >> 1) * 64 : wave * 32;
  const int lr = lane & 15, lqd = lane >> 4;
  v4f acc[NI][NJ];
#pragma unroll
  for (int i = 0; i < NI; i++)
#pragma unroll
    for (int j = 0; j < NJ; j++) acc[i][j] = (v4f){0.f, 0.f, 0.f, 0.f};

  for (int k0 = 0; k0 < K; k0 += BK) {
#pragma unroll
    for (int s = 0; s < BM / 64; s++) {
      int c = s * 256 + tid;
      int row = c >> 2, kc = c & 3;
      const ushort* ga = A + (size_t)(tm + row) * K + k0 + kc * 8;
      __builtin_amdgcn_global_load_lds((const __attribute__((address_space(1))) void*)ga,
          (__attribute__((address_space(3))) void*)(As + (s * 256 + wave * 64) * 8), 16, 0, 0);
    }
#pragma unroll
    for (int s = 0; s < 2; s++) {
      int c = s * 256 + tid;
      int row = c >> 2, kc = c & 3;
      const ushort* gb = Bw + (size_t)(tn + row) * K + k0 + kc * 8;
      __builtin_amdgcn_global_load_lds((const __attribute__((address_space(1))) void*)gb,
          (__attribute__((address_space(3))) void*)(Bs + (s * 256 + wave * 64) * 8), 16, 0, 0);
    }
    __syncthreads();
    v8s af[NI], bfr[NJ];
#pragma unroll
    for (int i = 0; i < NI; i++)
      af[i] = *(const v8s*)(As + (wm + i * 16 + lr) * BK + lqd * 8);
#pragma unroll
    for (int j = 0; j < NJ; j++)
      bfr[j] = *(const v8s*)(Bs + (wn + j * 16 + lr) * BK + lqd * 8);
#pragma unroll
    for (int i = 0; i < NI; i++)
#pragma unroll
      for (int j = 0; j < NJ; j++)
        acc[i][j] = __builtin_amdgcn_mfma_f32_16x16x32_bf16(af[i], bfr[j], acc[i][j], 0, 0, 0);
    __syncthreads();
  }
  // paired epilogue: shfl_xor(1) pack -> even lanes store uint (2 bf16)
  const bool evenl = (lane & 1) == 0;
#pragma unroll
  for (int i = 0; i < NI; i++) {
#pragma unroll
    for (int j = 0; j < NJ; j++) {
      int col = tn + wn + j * 16 + lr;
      float bv = bias[col];
#pragma unroll
      for (int r = 0; r < 4; r++) {
        float v = acc[i][j][r] + bv;
        if (OUT == 2) v = fmaxf(v, 0.f);
        float vn = __shfl_xor(v, 1, 64);
        if (evenl) {
          uint32_t pk = (uint32_t)f2bf(v) | ((uint32_t)f2bf(vn) << 16);
          int row = tm + wm + i * 16 + lqd * 4 + r;
          *(uint32_t*)((ushort*)Cp + (size_t)row * N + col) = pk;
        }
      }
    }
  }
}

// ---------------- MFMA flash attention with rel-eb bias ----------------
// Column-permuted S tiles: MFMA j covers K rows 4*lr+j -> per-lane k-consecutive
// quads of S elements (uchar4 ids loads, b64 Ps stores). K staged via
// global_load_lds with an XOR chunk swizzle (LDS chunk r*8 + (kc ^ (r>>3 & 7)))
// so the permuted frag reads are 2-way (free). qrel bias via 4 MFMAs on the
// resident Q fragments. No-max softmax (scores bounded; clamped at 60).
template<bool CAUSAL>
__global__ __launch_bounds__(256)
void k_flash(const ushort* __restrict__ Q, const ushort* __restrict__ Kv,
             const ushort* __restrict__ Vv, const ushort* __restrict__ relkb,
             const float* __restrict__ relb, const unsigned char* __restrict__ ids8,
             ushort* __restrict__ Out, int Lk, int ldq, int ldkv) {
  constexpr int ST = 72;
  __shared__ __align__(16) ushort Ks[2][64 * 64];   // chunk-swizzled [row][64]
  __shared__ __align__(16) ushort Vt[DHd * ST];     // [dh][k], stride 72
  __shared__ __align__(16) ushort Ps[64 * ST];      // [q][k], stride 72
  __shared__ __align__(16) unsigned char ids_s[2][64 * 64];
  __shared__ float qb_s[64 * 33];                   // f32 stride 33: bank=(q+id)&31
  const int bh = blockIdx.y, b = bh >> 4, h = bh & 15;
  const int q0 = blockIdx.x * 64;
  const int tid = threadIdx.x, wave = tid >> 6, lane = tid & 63;
  const int lr = lane & 15, quad = lane >> 4;
  const int phi = lr >> 1; // K chunk-swizzle phase for rows 4*lr+j
  const int rq = tid >> 4, cc = tid & 15; // V-transpose roles
  const ushort* Qb = Q + (size_t)b * LQ * ldq + h * DHd;
  const ushort* Kb = Kv + (size_t)b * Lk * ldkv + h * DHd;
  const ushort* Vb = Vv + (size_t)b * Lk * ldkv + h * DHd;

  // Q fragments resident all kernel
  v8s qf0 = *(const v8s*)(Qb + (size_t)(q0 + wave * 16 + lr) * ldq + quad * 8);
  v8s qf1 = *(const v8s*)(Qb + (size_t)(q0 + wave * 16 + lr) * ldq + 32 + quad * 8);

  // K tile: 512 chunks of 16B. LDS chunk c holds global (row=c>>3, kc=(c&7)^((c>>6)&7)).
  auto dmaK = [&](int k0v, int bufi) {
#pragma unroll
    for (int s = 0; s < 2; s++) {
      int c = s * 256 + wave * 64 + lane;
      int row = c >> 3;
      int kc = (c & 7) ^ ((c >> 6) & 7);
      const ushort* g0 = Kb + (size_t)(k0v + row) * ldkv + kc * 8;
      __builtin_amdgcn_global_load_lds((const __attribute__((address_space(1))) void*)g0,
          (__attribute__((address_space(3))) void*)(&Ks[bufi][0] + (s * 256 + wave * 64) * 8), 16, 0, 0);
    }
  };
  auto dmaI = [&](int k0v, int bufi) {
    int c = wave * 64 + lane;
    int row = c >> 2, seg = c & 3;
    const unsigned char* g = ids8 + (size_t)(q0 + row) * Lk + k0v + seg * 16;
    __builtin_amdgcn_global_load_lds((const __attribute__((address_space(1))) void*)g,
        (__attribute__((address_space(3))) void*)(ids_s[bufi] + wave * 1024), 16, 0, 0);
  };
  ushort4 vr[4];
  auto loadV = [&](int k0v) {
    const ushort* vp = Vb + (size_t)(k0v + rq * 4) * ldkv + cc * 4;
#pragma unroll
    for (int i = 0; i < 4; i++) vr[i] = *(const ushort4*)(vp + (size_t)i * ldkv);
  };
  auto writeVt = [&]() {
    ushort4 w0 = {vr[0].x, vr[1].x, vr[2].x, vr[3].x};
    ushort4 w1 = {vr[0].y, vr[1].y, vr[2].y, vr[3].y};
    ushort4 w2 = {vr[0].z, vr[1].z, vr[2].z, vr[3].z};
    ushort4 w3 = {vr[0].w, vr[1].w, vr[2].w, vr[3].w};
    *(ushort4*)(Vt + (cc * 4 + 0) * ST + rq * 4) = w0;
    *(ushort4*)(Vt + (cc * 4 + 1) * ST + rq * 4) = w1;
    *(ushort4*)(Vt + (cc * 4 + 2) * ST + rq * 4) = w2;
    *(ushort4*)(Vt + (cc * 4 + 3) * ST + rq * 4) = w3;
  };

  // prologue staging
  dmaK(0, 0); dmaI(0, 0);
  loadV(0);

  // qrel bias table via MFMA: qb_s[q][r] = Q[q]·rel_k[r] + rel_b[r][h]
  {
    v4f z = (v4f){0.f, 0.f, 0.f, 0.f};
    v8s rk0a = *(const v8s*)(relkb + lr * 64 + quad * 8);
    v8s rk0b = *(const v8s*)(relkb + lr * 64 + 32 + quad * 8);
    v8s rk1a = *(const v8s*)(relkb + (lr + 16) * 64 + quad * 8);
    v8s rk1b = *(const v8s*)(relkb + (lr + 16) * 64 + 32 + quad * 8);
    v4f q0r = __builtin_amdgcn_mfma_f32_16x16x32_bf16(qf0, rk0a, z, 0, 0, 0);
    q0r = __builtin_amdgcn_mfma_f32_16x16x32_bf16(qf1, rk0b, q0r, 0, 0, 0);
    v4f q1r = __builtin_amdgcn_mfma_f32_16x16x32_bf16(qf0, rk1a, z, 0, 0, 0);
    q1r = __builtin_amdgcn_mfma_f32_16x16x32_bf16(qf1, rk1b, q1r, 0, 0, 0);
    float rb0 = relb[lr * Hh + h], rb1 = relb[(lr + 16) * Hh + h];
#pragma unroll
    for (int r = 0; r < 4; r++) {
      int q = wave * 16 + quad * 4 + r;
      qb_s[q * 33 + lr] = q0r[r] + rb0;
      qb_s[q * 33 + 16 + lr] = q1r[r] + rb1;
    }
  }

  v4f o[4];
#pragma unroll
  for (int f = 0; f < 4; f++) o[f] = (v4f){0.f, 0.f, 0.f, 0.f};
  float l_[4] = {0.f, 0.f, 0.f, 0.f};

  const int kend = CAUSAL ? (q0 + 64) : Lk;
  const int nit = kend >> 6;
  __syncthreads(); // staging + qb_s table complete

  for (int it = 0; it < nit; it++) {
    const int k0v = it << 6, buf = it & 1;
    const bool more = (it + 1 < nit);
    if (more) { dmaK(k0v + 64, buf ^ 1); dmaI(k0v + 64, buf ^ 1); }
    // S = Q K^T, MFMA j covers K rows 4*lr+j (col lr of frag j == k = 4*lr+j)
    v4f sa[4];
#pragma unroll
    for (int j = 0; j < 4; j++) {
      const int r = 4 * lr + j;
      const ushort* base = &Ks[buf][0];
      v8s kf0 = *(const v8s*)(base + (r * 8 + (quad ^ phi)) * 8);
      v8s kf1 = *(const v8s*)(base + (r * 8 + ((quad + 4) ^ phi)) * 8);
      v4f z = (v4f){0.f, 0.f, 0.f, 0.f};
      z = __builtin_amdgcn_mfma_f32_16x16x32_bf16(qf0, kf0, z, 0, 0, 0);
      z = __builtin_amdgcn_mfma_f32_16x16x32_bf16(qf1, kf1, z, 0, 0, 0);
      sa[j] = z;
    }
    writeVt();
    if (more) loadV(k0v + 64);
    // bias + mask + exp (no-max softmax), per row r: k = 4*lr + j
    const bool diag = CAUSAL && (k0v == q0);
    float p[4][4];
#pragma unroll
    for (int r = 0; r < 4; r++) {
      int q = wave * 16 + quad * 4 + r;
      uchar4 idv = *(const uchar4*)(ids_s[buf] + q * 64 + 4 * lr);
      float d0 = (sa[0][r] + qb_s[q * 33 + idv.x]) * 0.125f;
      float d1 = (sa[1][r] + qb_s[q * 33 + idv.y]) * 0.125f;
      float d2 = (sa[2][r] + qb_s[q * 33 + idv.z]) * 0.125f;
      float d3 = (sa[3][r] + qb_s[q * 33 + idv.w]) * 0.125f;
      if (diag) {
        int kb = 4 * lr;
        if (kb + 0 > q) d0 = -1e9f;
        if (kb + 1 > q) d1 = -1e9f;
        if (kb + 2 > q) d2 = -1e9f;
        if (kb + 3 > q) d3 = -1e9f;
      }
      p[r][0] = __expf(fminf(d0, 60.f));
      p[r][1] = __expf(fminf(d1, 60.f));
      p[r][2] = __expf(fminf(d2, 60.f));
      p[r][3] = __expf(fminf(d3, 60.f));
      float ts = (p[r][0] + p[r][1]) + (p[r][2] + p[r][3]);
      ts += __shfl_xor(ts, 1, 64);
      ts += __shfl_xor(ts, 2, 64);
      ts += __shfl_xor(ts, 4, 64);
      ts += __shfl_xor(ts, 8, 64);
      l_[r] += ts;
    }
    // pack P -> bf16 pairs via v_perm, store b64 per row
#pragma unroll
    for (int r = 0; r < 4; r++) {
      int q = wave * 16 + quad * 4 + r;
      uint32_t b0 = asu(p[r][0]) + 0x8000u, b1 = asu(p[r][1]) + 0x8000u;
      uint32_t b2 = asu(p[r][2]) + 0x8000u, b3 = asu(p[r][3]) + 0x8000u;
      uint2 pk;
      pk.x = __builtin_amdgcn_perm(b1, b0, 0x07060302u);
      pk.y = __builtin_amdgcn_perm(b3, b2, 0x07060302u);
      *(uint2*)(Ps + q * ST + 4 * lr) = pk;
    }
    __syncthreads(); // Vt + Ps visible
    // O += P V
    v8s pf0 = *(const v8s*)(Ps + (wave * 16 + lr) * ST + quad * 8);
    v8s pf1 = *(const v8s*)(Ps + (wave * 16 + lr) * ST + 32 + quad * 8);
#pragma unroll
    for (int f = 0; f < 4; f++) {
      v8s vf0 = *(const v8s*)(Vt + (f * 16 + lr) * ST + quad * 8);
      v8s vf1 = *(const v8s*)(Vt + (f * 16 + lr) * ST + 32 + quad * 8);
      o[f] = __builtin_amdgcn_mfma_f32_16x16x32_bf16(pf0, vf0, o[f], 0, 0, 0);
      o[f] = __builtin_amdgcn_mfma_f32_16x16x32_bf16(pf1, vf1, o[f], 0, 0, 0);
    }
    __syncthreads(); // PV reads done before Vt/Ks/ids overwrite
  }
#pragma unroll
  for (int r = 0; r < 4; r++) {
    float inv = 1.f / l_[r];
    int qabs = q0 + wave * 16 + quad * 4 + r;
    ushort* op = Out + ((size_t)b * LQ + qabs) * Dm + h * DHd + lr;
#pragma unroll
    for (int f = 0; f < 4; f++)
      op[f * 16] = f2bf(o[f][r] * inv);
  }
}

// ---------------- fused residual add + LayerNorm (attn/ffn branch in bf16) ----------------
__global__ __launch_bounds__(256)
void k_addln(const float* __restrict__ res, const ushort* __restrict__ xin,
             const float* __restrict__ gw, const float* __restrict__ bw,
             float* __restrict__ yout, ushort* __restrict__ ybf) {
  const int row = blockIdx.x, t = threadIdx.x;
  float4 a = *(const float4*)(res + (size_t)row * Dm + t * 4);
  ushort4 cu = *(const ushort4*)(xin + (size_t)row * Dm + t * 4);
  float v0 = a.x + bf2f(cu.x), v1 = a.y + bf2f(cu.y), v2 = a.z + bf2f(cu.z), v3 = a.w + bf2f(cu.w);
  float s = v0 + v1 + v2 + v3;
  float q = v0 * v0 + v1 * v1 + v2 * v2 + v3 * v3;
#pragma unroll
  for (int o = 32; o > 0; o >>= 1) { s += __shfl_xor(s, o, 64); q += __shfl_xor(q, o, 64); }
  __shared__ float sb[4], qb[4];
  if ((t & 63) == 0) { sb[t >> 6] = s; qb[t >> 6] = q; }
  __syncthreads();
  s = sb[0] + sb[1] + sb[2] + sb[3];
  q = qb[0] + qb[1] + qb[2] + qb[3];
  const float mean = s * (1.f / Dm);
  const float var = q * (1.f / Dm) - mean * mean;
  const float inv = rsqrtf(var + 1e-5f);
  float4 g4 = *(const float4*)(gw + t * 4);
  float4 b4 = *(const float4*)(bw + t * 4);
  float o0 = (v0 - mean) * inv * g4.x + b4.x;
  float o1 = (v1 - mean) * inv * g4.y + b4.y;
  float o2 = (v2 - mean) * inv * g4.z + b4.z;
  float o3 = (v3 - mean) * inv * g4.w + b4.w;
  float4 o = {o0, o1, o2, o3};
  *(float4*)(yout + (size_t)row * Dm + t * 4) = o;
  if (ybf) {
    ushort4 u; u.x = f2bf(o0); u.y = f2bf(o1); u.z = f2bf(o2); u.w = f2bf(o3);
    *(ushort4*)(ybf + (size_t)row * Dm + t * 4) = u;
  }
}

extern "C" void kernel_launch(void* const* d_in, const int* in_sizes, int n_in,
                              void* d_out, int out_size, void* d_ws, size_t ws_size,
                              hipStream_t stream) {
  (void)in_sizes; (void)n_in; (void)out_size; (void)ws_size;
  const float* x     = (const float*)d_in[0];
  const float* enc   = (const float*)d_in[1];
  const int*   ids1  = (const int*)d_in[2];
  const int*   ids2  = (const int*)d_in[3];
  const float* wq1 = (const float*)d_in[6],  *wk1 = (const float*)d_in[7];
  const float* wv1 = (const float*)d_in[8],  *wo1 = (const float*)d_in[9];
  const float* bq1 = (const float*)d_in[10], *bk1 = (const float*)d_in[11];
  const float* bv1 = (const float*)d_in[12], *bo1 = (const float*)d_in[13];
  const float* relk1 = (const float*)d_in[14], *relb1 = (const float*)d_in[15];
  const float* wq2 = (const float*)d_in[16], *wk2 = (const float*)d_in[17];
  const float* wv2 = (const float*)d_in[18], *wo2 = (const float*)d_in[19];
  const float* bq2 = (const float*)d_in[20], *bk2 = (const float*)d_in[21];
  const float* bv2 = (const float*)d_in[22], *bo2 = (const float*)d_in[23];
  const float* relk2 = (const float*)d_in[24], *relb2 = (const float*)d_in[25];
  const float* w1 = (const float*)d_in[26], *b1 = (const float*)d_in[27];
  const float* w2 = (const float*)d_in[28], *b2 = (const float*)d_in[29];
  const float* g1 = (const float*)d_in[30], *be1 = (const float*)d_in[31];
  const float* g2 = (const float*)d_in[32], *be2 = (const float*)d_in[33];
  const float* g3 = (const float*)d_in[34], *be3 = (const float*)d_in[35];

  char* W = (char*)d_ws;
  const size_t MB = 1u << 20;
  ushort* wqkv1b = (ushort*)(W + 0 * MB);   // 6 MB  [3072][1024]
  ushort* wo1b   = (ushort*)(W + 6 * MB);   // 2
  ushort* wq2b   = (ushort*)(W + 8 * MB);   // 2
  ushort* wkv2b  = (ushort*)(W + 10 * MB);  // 4   [2048][1024]
  ushort* wo2b   = (ushort*)(W + 14 * MB);  // 2
  ushort* w1b    = (ushort*)(W + 16 * MB);  // 8
  ushort* w2b    = (ushort*)(W + 24 * MB);  // 8
  ushort* xb     = (ushort*)(W + 32 * MB);  // 8 (self phase); yb reuses after
  ushort* yb     = (ushort*)(W + 32 * MB);
  ushort* encb   = (ushort*)(W + 40 * MB);  // 8
  ushort* qkv    = (ushort*)(W + 48 * MB);  // 24 (self)
  ushort* q8c    = (ushort*)(W + 48 * MB);
  ushort* ffh    = (ushort*)(W + 48 * MB);  // 32 (FFN)
  ushort* kv2    = (ushort*)(W + 80 * MB);  // 16 (cross)
  ushort* t8     = (ushort*)(W + 80 * MB);  // 8  (sequentially reused)
  ushort* attb   = (ushort*)(W + 96 * MB);  // 8
  ushort* relkb1 = (ushort*)(W + 104 * MB);            // 4 KB
  ushort* relkb2 = (ushort*)(W + 104 * MB + 8192);     // 4 KB
  unsigned char* ids8a = (unsigned char*)(W + 108 * MB); // 1
  unsigned char* ids8b = (unsigned char*)(W + 109 * MB); // 1
  float* bqkv1   = (float*)(W + 110 * MB);               // 12 KB
  float* bkv2    = (float*)(W + 110 * MB + 65536);       // 8 KB
  float* y       = (float*)(W + 111 * MB); // 16 -> ends 127 MB

  // ---- converts (single segmented launch) ----
  CvtArgs ca;
  const float* srcs[14] = {x, enc, wq1, wk1, wv1, wo1, wq2, wk2, wv2, wo2, w1, w2, relk1, relk2};
  ushort* dsts[14] = {xb, encb, wqkv1b, wqkv1b + 1024 * 1024, wqkv1b + 2 * 1024 * 1024,
                      wo1b, wq2b, wkv2b, wkv2b + 1024 * 1024, wo2b, w1b, w2b, relkb1, relkb2};
  int lens[14] = {ROWS * Dm, ROWS * Dm, Dm * Dm, Dm * Dm, Dm * Dm, Dm * Dm,
                  Dm * Dm, Dm * Dm, Dm * Dm, Dm * Dm, FFd * Dm, Dm * FFd, NR * DHd, NR * DHd};
  int cum = 0;
  for (int i = 0; i < 14; i++) { ca.src[i] = srcs[i]; ca.dst[i] = dsts[i]; ca.cum[i] = cum; cum += lens[i] >> 2; }
  ca.cum[14] = cum;
  k_cvt_all<<<dim3((cum + 255) / 256), 256, 0, stream>>>(ca);
  k_bias<<<dim3(20), 256, 0, stream>>>(bq1, bk1, bv1, bk2, bv2, bqkv1, bkv2);
  k_ids8<<<dim3(2048), 256, 0, stream>>>(ids1, ids2, ids8a, ids8b);

  auto gemm = [&](int mode, int bm, const ushort* A, const ushort* Bw, const float* bias,
                  void* C, int M, int N, int K) {
    dim3 g((M / bm) * (N / 128));
    if (bm == 128) {
      if (mode == 1) k_gemm<1, 128><<<g, 256, 0, stream>>>(A, Bw, bias, C, M, N, K);
      else           k_gemm<2, 128><<<g, 256, 0, stream>>>(A, Bw, bias, C, M, N, K);
    } else {
      k_gemm<1, 64><<<g, 256, 0, stream>>>(A, Bw, bias, C, M, N, K);
    }
  };

  // ---- self attention ----
  gemm(1, 128, xb, wqkv1b, bqkv1, qkv, ROWS, 3072, Dm);
  k_flash<true><<<dim3(LQ / 64, Bn * Hh), 256, 0, stream>>>(
      qkv, qkv + 1024, qkv + 2048, relkb1, relb1, ids8a, attb, LQ, 3072, 3072);
  gemm(1, 64, attb, wo1b, bo1, t8, ROWS, 1024, Dm);
  k_addln<<<dim3(ROWS), 256, 0, stream>>>(x, t8, g1, be1, y, yb);

  // ---- cross attention ----
  gemm(1, 64, yb, wq2b, bq2, q8c, ROWS, 1024, Dm);
  gemm(1, 128, encb, wkv2b, bkv2, kv2, ROWS, 2048, Dm);
  k_flash<false><<<dim3(LQ / 64, Bn * Hh), 256, 0, stream>>>(
      q8c, kv2, kv2 + 1024, relkb2, relb2, ids8b, attb, LQ, 1024, 2048);
  gemm(1, 64, attb, wo2b, bo2, t8, ROWS, 1024, Dm);
  k_addln<<<dim3(ROWS), 256, 0, stream>>>(y, t8, g2, be2, y, yb);

  // ---- FFN ----
  gemm(2, 128, yb, w1b, b1, ffh, ROWS, FFd, Dm);
  gemm(1, 64, ffh, w2b, b2, t8, ROWS, 1024, FFd);
  k_addln<<<dim3(ROWS), 256, 0, stream>>>(y, t8, g3, be3, (float*)d_out, nullptr);
}

// Round 7
// 624.274 us; speedup vs baseline: 1.0672x; 1.0672x over previous
//
#include <hip/hip_runtime.h>
#include <cstdint>
#include <cstddef>

#define DEV static __device__ __forceinline__

constexpr int Bn = 4, LQ = 1024, Dm = 1024, Hh = 16, FFd = 4096, DHd = 64, NR = 32;
constexpr int ROWS = Bn * LQ; // 4096

typedef __attribute__((ext_vector_type(8))) short v8s;
typedef __attribute__((ext_vector_type(4))) float v4f;

DEV float bf2f(ushort u) { union { uint32_t i; float f; } w; w.i = ((uint32_t)u) << 16; return w.f; }
DEV ushort f2bf(float f) {
  union { float f; uint32_t i; } w; w.f = f;
  uint32_t r = w.i + 0x7fffu + ((w.i >> 16) & 1u);
  return (ushort)(r >> 16);
}
DEV uint32_t asu(float f) { union { float f; uint32_t i; } w; w.f = f; return w.i; }

// ---------------- segmented f32 -> bf16 convert (one launch for all inputs) ----------------
struct CvtArgs {
  const float* src[14];
  ushort* dst[14];
  int cum[15]; // cumulative float4-task offsets
};
__global__ __launch_bounds__(256)
void k_cvt_all(CvtArgs a) {
  int t = blockIdx.x * 256 + threadIdx.x;
  if (t >= a.cum[14]) return;
  int seg = 0;
#pragma unroll
  for (int s = 1; s < 14; s++) if (t >= a.cum[s]) seg = s;
  int u = t - a.cum[seg];
  float4 v = *(const float4*)(a.src[seg] + (size_t)u * 4);
  ushort4 w; w.x = f2bf(v.x); w.y = f2bf(v.y); w.z = f2bf(v.z); w.w = f2bf(v.w);
  *(ushort4*)(a.dst[seg] + (size_t)u * 4) = w;
}

// ---------------- bias concat: bqkv1[3072], bkv2[2048] ----------------
__global__ __launch_bounds__(256)
void k_bias(const float* __restrict__ bq1, const float* __restrict__ bk1, const float* __restrict__ bv1,
            const float* __restrict__ bk2, const float* __restrict__ bv2,
            float* __restrict__ o1, float* __restrict__ o2) {
  int t = blockIdx.x * 256 + threadIdx.x;
  if (t < 3072) o1[t] = t < 1024 ? bq1[t] : (t < 2048 ? bk1[t - 1024] : bv1[t - 2048]);
  else if (t < 5120) { int u = t - 3072; o2[u] = u < 1024 ? bk2[u] : bv2[u - 1024]; }
}

// ---------------- ids -> u8 (natural layout) ----------------
__global__ __launch_bounds__(256)
void k_ids8(const int* __restrict__ i1, const int* __restrict__ i2,
            unsigned char* __restrict__ o1, unsigned char* __restrict__ o2) {
  int t = blockIdx.x * 256 + threadIdx.x;
  const int n = LQ * LQ / 4;
  if (t >= 2 * n) return;
  const int* ip = t < n ? i1 : i2;
  unsigned char* op = t < n ? o1 : o2;
  int u = t < n ? t : t - n;
  int q = u >> 8;
  int k4 = (u & 255) * 4;
  int4 v = *(const int4*)(ip + (size_t)q * LQ + k4);
  uchar4 pk; pk.x = (unsigned char)v.x; pk.y = (unsigned char)v.y;
  pk.z = (unsigned char)v.z; pk.w = (unsigned char)v.w;
  *(uchar4*)(op + (size_t)q * LQ + k4) = pk;
}

// ---------------- bf16 GEMM: C[M,N] = A[M,K] * Bw[N,K]^T + bias ----------------
// Double-buffered global_load_lds staging: issue tile k+1's DMA after the
// barrier, compute tile k, one barrier/iter. The barrier's vmcnt(0) drain
// then covers loads that aged a full compute phase (vs 0 cyc in the m97
// 2-barrier form) — the fix for the latency-bound profile (MfmaUtil 15%,
// VALUBusy 16%, 2 blocks/CU). XCD-slab swizzle + paired bf16 stores kept.
// OUT: 1 = bf16, 2 = bf16 + relu. BM=128 or 64.
template<int OUT, int BM>
__global__ __launch_bounds__(256)
void k_gemm(const ushort* __restrict__ A, const ushort* __restrict__ Bw,
            const float* __restrict__ bias, void* __restrict__ Cp,
            int M, int N, int K) {
  constexpr int BN = 128, BK = 32;
  constexpr int NI = 4, NJ = (BM == 128) ? 4 : 2;
  __shared__ __align__(16) ushort As[2][BM * BK];
  __shared__ __align__(16) ushort Bs[2][BN * BK];
  const int nN = N >> 7, k8 = nN >> 3;
  const int bid = blockIdx.x;
  const int xcd = bid & 7, sb = bid >> 3;
  const int tn = (xcd + ((sb % k8) << 3)) << 7;  // tn cycles fastest on each XCD
  const int tm = (sb / k8) * BM;
  const int tid = threadIdx.x;
  const int wave = tid >> 6, lane = tid & 63;
  const int wm = (BM == 128) ? (wave & 1) * 64 : 0;
  const int wn = (BM == 128) ? (wave >> 1) * 64 : wave * 32;
  const int lr = lane & 15, lqd = lane >> 4;

  auto dma = [&](int k0, int bufi) {
#pragma unroll
    for (int s = 0; s < BM / 64; s++) {
      int c = s * 256 + tid;
      int row = c >> 2, kc = c & 3;
      const ushort* ga = A + (size_t)(tm + row) * K + k0 + kc * 8;
      __builtin_amdgcn_global_load_lds((const __attribute__((address_space(1))) void*)ga,
          (__attribute__((address_space(3))) void*)(&As[bufi][0] + (s * 256 + wave * 64) * 8), 16, 0, 0);
    }
#pragma unroll
    for (int s = 0; s < 2; s++) {
      int c = s * 256 + tid;
      int row = c >> 2, kc = c & 3;
      const ushort* gb = Bw + (size_t)(tn + row) * K + k0 + kc * 8;
      __builtin_amdgcn_global_load_lds((const __attribute__((address_space(1))) void*)gb,
          (__attribute__((address_space(3))) void*)(&Bs[bufi][0] + (s * 256 + wave * 64) * 8), 16, 0, 0);
    }
  };

  v4f acc[NI][NJ];
#pragma unroll
  for (int i = 0; i < NI; i++)
#pragma unroll
    for (int j = 0; j < NJ; j++) acc[i][j] = (v4f){0.f, 0.f, 0.f, 0.f};

  const int nit = K / BK;
  dma(0, 0);
  for (int it = 0; it < nit; it++) {
    const int buf = it & 1;
    __syncthreads();                 // drains buf's DMA; WAR-safe for buf^1
    if (it + 1 < nit) dma((it + 1) * BK, buf ^ 1);
    v8s af[NI], bfr[NJ];
#pragma unroll
    for (int i = 0; i < NI; i++)
      af[i] = *(const v8s*)(&As[buf][0] + (wm + i * 16 + lr) * BK + lqd * 8);
#pragma unroll
    for (int j = 0; j < NJ; j++)
      bfr[j] = *(const v8s*)(&Bs[buf][0] + (wn + j * 16 + lr) * BK + lqd * 8);
#pragma unroll
    for (int i = 0; i < NI; i++)
#pragma unroll
      for (int j = 0; j < NJ; j++)
        acc[i][j] = __builtin_amdgcn_mfma_f32_16x16x32_bf16(af[i], bfr[j], acc[i][j], 0, 0, 0);
  }
  // paired epilogue: shfl_xor(1) pack -> even lanes store uint (2 bf16)
  const bool evenl = (lane & 1) == 0;
#pragma unroll
  for (int i = 0; i < NI; i++) {
#pragma unroll
    for (int j = 0; j < NJ; j++) {
      int col = tn + wn + j * 16 + lr;
      float bv = bias[col];
#pragma unroll
      for (int r = 0; r < 4; r++) {
        float v = acc[i][j][r] + bv;
        if (OUT == 2) v = fmaxf(v, 0.f);
        float vn = __shfl_xor(v, 1, 64);
        if (evenl) {
          uint32_t pk = (uint32_t)f2bf(v) | ((uint32_t)f2bf(vn) << 16);
          int row = tm + wm + i * 16 + lqd * 4 + r;
          *(uint32_t*)((ushort*)Cp + (size_t)row * N + col) = pk;
        }
      }
    }
  }
}

// ---------------- MFMA flash attention with rel-eb bias ----------------
// Column-permuted S tiles: MFMA j covers K rows 4*lr+j -> per-lane k-consecutive
// quads of S elements (uchar4 ids loads, b64 Ps stores). K staged via
// global_load_lds with an XOR chunk swizzle (LDS chunk r*8 + (kc ^ (r>>3 & 7)))
// so the permuted frag reads are 2-way (free). qrel bias via 4 MFMAs on the
// resident Q fragments. No-max softmax (scores bounded; clamped at 60).
template<bool CAUSAL>
__global__ __launch_bounds__(256)
void k_flash(const ushort* __restrict__ Q, const ushort* __restrict__ Kv,
             const ushort* __restrict__ Vv, const ushort* __restrict__ relkb,
             const float* __restrict__ relb, const unsigned char* __restrict__ ids8,
             ushort* __restrict__ Out, int Lk, int ldq, int ldkv) {
  constexpr int ST = 72;
  __shared__ __align__(16) ushort Ks[2][64 * 64];   // chunk-swizzled [row][64]
  __shared__ __align__(16) ushort Vt[DHd * ST];     // [dh][k], stride 72
  __shared__ __align__(16) ushort Ps[64 * ST];      // [q][k], stride 72
  __shared__ __align__(16) unsigned char ids_s[2][64 * 64];
  __shared__ float qb_s[64 * 33];                   // f32 stride 33: bank=(q+id)&31
  const int bh = blockIdx.y, b = bh >> 4, h = bh & 15;
  const int q0 = blockIdx.x * 64;
  const int tid = threadIdx.x, wave = tid >> 6, lane = tid & 63;
  const int lr = lane & 15, quad = lane >> 4;
  const int phi = lr >> 1; // K chunk-swizzle phase for rows 4*lr+j
  const int rq = tid >> 4, cc = tid & 15; // V-transpose roles
  const ushort* Qb = Q + (size_t)b * LQ * ldq + h * DHd;
  const ushort* Kb = Kv + (size_t)b * Lk * ldkv + h * DHd;
  const ushort* Vb = Vv + (size_t)b * Lk * ldkv + h * DHd;

  // Q fragments resident all kernel
  v8s qf0 = *(const v8s*)(Qb + (size_t)(q0 + wave * 16 + lr) * ldq + quad * 8);
  v8s qf1 = *(const v8s*)(Qb + (size_t)(q0 + wave * 16 + lr) * ldq + 32 + quad * 8);

  // K tile: 512 chunks of 16B. LDS chunk c holds global (row=c>>3, kc=(c&7)^((c>>6)&7)).
  auto dmaK = [&](int k0v, int bufi) {
#pragma unroll
    for (int s = 0; s < 2; s++) {
      int c = s * 256 + wave * 64 + lane;
      int row = c >> 3;
      int kc = (c & 7) ^ ((c >> 6) & 7);
      const ushort* g0 = Kb + (size_t)(k0v + row) * ldkv + kc * 8;
      __builtin_amdgcn_global_load_lds((const __attribute__((address_space(1))) void*)g0,
          (__attribute__((address_space(3))) void*)(&Ks[bufi][0] + (s * 256 + wave * 64) * 8), 16, 0, 0);
    }
  };
  auto dmaI = [&](int k0v, int bufi) {
    int c = wave * 64 + lane;
    int row = c >> 2, seg = c & 3;
    const unsigned char* g = ids8 + (size_t)(q0 + row) * Lk + k0v + seg * 16;
    __builtin_amdgcn_global_load_lds((const __attribute__((address_space(1))) void*)g,
        (__attribute__((address_space(3))) void*)(ids_s[bufi] + wave * 1024), 16, 0, 0);
  };
  ushort4 vr[4];
  auto loadV = [&](int k0v) {
    const ushort* vp = Vb + (size_t)(k0v + rq * 4) * ldkv + cc * 4;
#pragma unroll
    for (int i = 0; i < 4; i++) vr[i] = *(const ushort4*)(vp + (size_t)i * ldkv);
  };
  auto writeVt = [&]() {
    ushort4 w0 = {vr[0].x, vr[1].x, vr[2].x, vr[3].x};
    ushort4 w1 = {vr[0].y, vr[1].y, vr[2].y, vr[3].y};
    ushort4 w2 = {vr[0].z, vr[1].z, vr[2].z, vr[3].z};
    ushort4 w3 = {vr[0].w, vr[1].w, vr[2].w, vr[3].w};
    *(ushort4*)(Vt + (cc * 4 + 0) * ST + rq * 4) = w0;
    *(ushort4*)(Vt + (cc * 4 + 1) * ST + rq * 4) = w1;
    *(ushort4*)(Vt + (cc * 4 + 2) * ST + rq * 4) = w2;
    *(ushort4*)(Vt + (cc * 4 + 3) * ST + rq * 4) = w3;
  };

  // prologue staging
  dmaK(0, 0); dmaI(0, 0);
  loadV(0);

  // qrel bias table via MFMA: qb_s[q][r] = Q[q]·rel_k[r] + rel_b[r][h]
  {
    v4f z = (v4f){0.f, 0.f, 0.f, 0.f};
    v8s rk0a = *(const v8s*)(relkb + lr * 64 + quad * 8);
    v8s rk0b = *(const v8s*)(relkb + lr * 64 + 32 + quad * 8);
    v8s rk1a = *(const v8s*)(relkb + (lr + 16) * 64 + quad * 8);
    v8s rk1b = *(const v8s*)(relkb + (lr + 16) * 64 + 32 + quad * 8);
    v4f q0r = __builtin_amdgcn_mfma_f32_16x16x32_bf16(qf0, rk0a, z, 0, 0, 0);
    q0r = __builtin_amdgcn_mfma_f32_16x16x32_bf16(qf1, rk0b, q0r, 0, 0, 0);
    v4f q1r = __builtin_amdgcn_mfma_f32_16x16x32_bf16(qf0, rk1a, z, 0, 0, 0);
    q1r = __builtin_amdgcn_mfma_f32_16x16x32_bf16(qf1, rk1b, q1r, 0, 0, 0);
    float rb0 = relb[lr * Hh + h], rb1 = relb[(lr + 16) * Hh + h];
#pragma unroll
    for (int r = 0; r < 4; r++) {
      int q = wave * 16 + quad * 4 + r;
      qb_s[q * 33 + lr] = q0r[r] + rb0;
      qb_s[q * 33 + 16 + lr] = q1r[r] + rb1;
    }
  }

  v4f o[4];
#pragma unroll
  for (int f = 0; f < 4; f++) o[f] = (v4f){0.f, 0.f, 0.f, 0.f};
  float l_[4] = {0.f, 0.f, 0.f, 0.f};

  const int kend = CAUSAL ? (q0 + 64) : Lk;
  const int nit = kend >> 6;
  __syncthreads(); // staging + qb_s table complete

  for (int it = 0; it < nit; it++) {
    const int k0v = it << 6, buf = it & 1;
    const bool more = (it + 1 < nit);
    if (more) { dmaK(k0v + 64, buf ^ 1); dmaI(k0v + 64, buf ^ 1); }
    // S = Q K^T, MFMA j covers K rows 4*lr+j (col lr of frag j == k = 4*lr+j)
    v4f sa[4];
#pragma unroll
    for (int j = 0; j < 4; j++) {
      const int r = 4 * lr + j;
      const ushort* base = &Ks[buf][0];
      v8s kf0 = *(const v8s*)(base + (r * 8 + (quad ^ phi)) * 8);
      v8s kf1 = *(const v8s*)(base + (r * 8 + ((quad + 4) ^ phi)) * 8);
      v4f z = (v4f){0.f, 0.f, 0.f, 0.f};
      z = __builtin_amdgcn_mfma_f32_16x16x32_bf16(qf0, kf0, z, 0, 0, 0);
      z = __builtin_amdgcn_mfma_f32_16x16x32_bf16(qf1, kf1, z, 0, 0, 0);
      sa[j] = z;
    }
    writeVt();
    if (more) loadV(k0v + 64);
    // bias + mask + exp (no-max softmax), per row r: k = 4*lr + j
    const bool diag = CAUSAL && (k0v == q0);
    float p[4][4];
#pragma unroll
    for (int r = 0; r < 4; r++) {
      int q = wave * 16 + quad * 4 + r;
      uchar4 idv = *(const uchar4*)(ids_s[buf] + q * 64 + 4 * lr);
      float d0 = (sa[0][r] + qb_s[q * 33 + idv.x]) * 0.125f;
      float d1 = (sa[1][r] + qb_s[q * 33 + idv.y]) * 0.125f;
      float d2 = (sa[2][r] + qb_s[q * 33 + idv.z]) * 0.125f;
      float d3 = (sa[3][r] + qb_s[q * 33 + idv.w]) * 0.125f;
      if (diag) {
        int kb = 4 * lr;
        if (kb + 0 > q) d0 = -1e9f;
        if (kb + 1 > q) d1 = -1e9f;
        if (kb + 2 > q) d2 = -1e9f;
        if (kb + 3 > q) d3 = -1e9f;
      }
      p[r][0] = __expf(fminf(d0, 60.f));
      p[r][1] = __expf(fminf(d1, 60.f));
      p[r][2] = __expf(fminf(d2, 60.f));
      p[r][3] = __expf(fminf(d3, 60.f));
      float ts = (p[r][0] + p[r][1]) + (p[r][2] + p[r][3]);
      ts += __shfl_xor(ts, 1, 64);
      ts += __shfl_xor(ts, 2, 64);
      ts += __shfl_xor(ts, 4, 64);
      ts += __shfl_xor(ts, 8, 64);
      l_[r] += ts;
    }
    // pack P -> bf16 pairs via v_perm, store b64 per row
#pragma unroll
    for (int r = 0; r < 4; r++) {
      int q = wave * 16 + quad * 4 + r;
      uint32_t b0 = asu(p[r][0]) + 0x8000u, b1 = asu(p[r][1]) + 0x8000u;
      uint32_t b2 = asu(p[r][2]) + 0x8000u, b3 = asu(p[r][3]) + 0x8000u;
      uint2 pk;
      pk.x = __builtin_amdgcn_perm(b1, b0, 0x07060302u);
      pk.y = __builtin_amdgcn_perm(b3, b2, 0x07060302u);
      *(uint2*)(Ps + q * ST + 4 * lr) = pk;
    }
    __syncthreads(); // Vt + Ps visible
    // O += P V
    v8s pf0 = *(const v8s*)(Ps + (wave * 16 + lr) * ST + quad * 8);
    v8s pf1 = *(const v8s*)(Ps + (wave * 16 + lr) * ST + 32 + quad * 8);
#pragma unroll
    for (int f = 0; f < 4; f++) {
      v8s vf0 = *(const v8s*)(Vt + (f * 16 + lr) * ST + quad * 8);
      v8s vf1 = *(const v8s*)(Vt + (f * 16 + lr) * ST + 32 + quad * 8);
      o[f] = __builtin_amdgcn_mfma_f32_16x16x32_bf16(pf0, vf0, o[f], 0, 0, 0);
      o[f] = __builtin_amdgcn_mfma_f32_16x16x32_bf16(pf1, vf1, o[f], 0, 0, 0);
    }
    __syncthreads(); // PV reads done before Vt/Ks/ids overwrite
  }
#pragma unroll
  for (int r = 0; r < 4; r++) {
    float inv = 1.f / l_[r];
    int qabs = q0 + wave * 16 + quad * 4 + r;
    ushort* op = Out + ((size_t)b * LQ + qabs) * Dm + h * DHd + lr;
#pragma unroll
    for (int f = 0; f < 4; f++)
      op[f * 16] = f2bf(o[f][r] * inv);
  }
}

// ---------------- fused residual add + LayerNorm (attn/ffn branch in bf16) ----------------
__global__ __launch_bounds__(256)
void k_addln(const float* __restrict__ res, const ushort* __restrict__ xin,
             const float* __restrict__ gw, const float* __restrict__ bw,
             float* __restrict__ yout, ushort* __restrict__ ybf) {
  const int row = blockIdx.x, t = threadIdx.x;
  float4 a = *(const float4*)(res + (size_t)row * Dm + t * 4);
  ushort4 cu = *(const ushort4*)(xin + (size_t)row * Dm + t * 4);
  float v0 = a.x + bf2f(cu.x), v1 = a.y + bf2f(cu.y), v2 = a.z + bf2f(cu.z), v3 = a.w + bf2f(cu.w);
  float s = v0 + v1 + v2 + v3;
  float q = v0 * v0 + v1 * v1 + v2 * v2 + v3 * v3;
#pragma unroll
  for (int o = 32; o > 0; o >>= 1) { s += __shfl_xor(s, o, 64); q += __shfl_xor(q, o, 64); }
  __shared__ float sb[4], qb[4];
  if ((t & 63) == 0) { sb[t >> 6] = s; qb[t >> 6] = q; }
  __syncthreads();
  s = sb[0] + sb[1] + sb[2] + sb[3];
  q = qb[0] + qb[1] + qb[2] + qb[3];
  const float mean = s * (1.f / Dm);
  const float var = q * (1.f / Dm) - mean * mean;
  const float inv = rsqrtf(var + 1e-5f);
  float4 g4 = *(const float4*)(gw + t * 4);
  float4 b4 = *(const float4*)(bw + t * 4);
  float o0 = (v0 - mean) * inv * g4.x + b4.x;
  float o1 = (v1 - mean) * inv * g4.y + b4.y;
  float o2 = (v2 - mean) * inv * g4.z + b4.z;
  float o3 = (v3 - mean) * inv * g4.w + b4.w;
  float4 o = {o0, o1, o2, o3};
  *(float4*)(yout + (size_t)row * Dm + t * 4) = o;
  if (ybf) {
    ushort4 u; u.x = f2bf(o0); u.y = f2bf(o1); u.z = f2bf(o2); u.w = f2bf(o3);
    *(ushort4*)(ybf + (size_t)row * Dm + t * 4) = u;
  }
}

extern "C" void kernel_launch(void* const* d_in, const int* in_sizes, int n_in,
                              void* d_out, int out_size, void* d_ws, size_t ws_size,
                              hipStream_t stream) {
  (void)in_sizes; (void)n_in; (void)out_size; (void)ws_size;
  const float* x     = (const float*)d_in[0];
  const float* enc   = (const float*)d_in[1];
  const int*   ids1  = (const int*)d_in[2];
  const int*   ids2  = (const int*)d_in[3];
  const float* wq1 = (const float*)d_in[6],  *wk1 = (const float*)d_in[7];
  const float* wv1 = (const float*)d_in[8],  *wo1 = (const float*)d_in[9];
  const float* bq1 = (const float*)d_in[10], *bk1 = (const float*)d_in[11];
  const float* bv1 = (const float*)d_in[12], *bo1 = (const float*)d_in[13];
  const float* relk1 = (const float*)d_in[14], *relb1 = (const float*)d_in[15];
  const float* wq2 = (const float*)d_in[16], *wk2 = (const float*)d_in[17];
  const float* wv2 = (const float*)d_in[18], *wo2 = (const float*)d_in[19];
  const float* bq2 = (const float*)d_in[20], *bk2 = (const float*)d_in[21];
  const float* bv2 = (const float*)d_in[22], *bo2 = (const float*)d_in[23];
  const float* relk2 = (const float*)d_in[24], *relb2 = (const float*)d_in[25];
  const float* w1 = (const float*)d_in[26], *b1 = (const float*)d_in[27];
  const float* w2 = (const float*)d_in[28], *b2 = (const float*)d_in[29];
  const float* g1 = (const float*)d_in[30], *be1 = (const float*)d_in[31];
  const float* g2 = (const float*)d_in[32], *be2 = (const float*)d_in[33];
  const float* g3 = (const float*)d_in[34], *be3 = (const float*)d_in[35];

  char* W = (char*)d_ws;
  const size_t MB = 1u << 20;
  ushort* wqkv1b = (ushort*)(W + 0 * MB);   // 6 MB  [3072][1024]
  ushort* wo1b   = (ushort*)(W + 6 * MB);   // 2
  ushort* wq2b   = (ushort*)(W + 8 * MB);   // 2
  ushort* wkv2b  = (ushort*)(W + 10 * MB);  // 4   [2048][1024]
  ushort* wo2b   = (ushort*)(W + 14 * MB);  // 2
  ushort* w1b    = (ushort*)(W + 16 * MB);  // 8
  ushort* w2b    = (ushort*)(W + 24 * MB);  // 8
  ushort* xb     = (ushort*)(W + 32 * MB);  // 8 (self phase); yb reuses after
  ushort* yb     = (ushort*)(W + 32 * MB);
  ushort* encb   = (ushort*)(W + 40 * MB);  // 8
  ushort* qkv    = (ushort*)(W + 48 * MB);  // 24 (self)
  ushort* q8c    = (ushort*)(W + 48 * MB);
  ushort* ffh    = (ushort*)(W + 48 * MB);  // 32 (FFN)
  ushort* kv2    = (ushort*)(W + 80 * MB);  // 16 (cross)
  ushort* t8     = (ushort*)(W + 80 * MB);  // 8  (sequentially reused)
  ushort* attb   = (ushort*)(W + 96 * MB);  // 8
  ushort* relkb1 = (ushort*)(W + 104 * MB);            // 4 KB
  ushort* relkb2 = (ushort*)(W + 104 * MB + 8192);     // 4 KB
  unsigned char* ids8a = (unsigned char*)(W + 108 * MB); // 1
  unsigned char* ids8b = (unsigned char*)(W + 109 * MB); // 1
  float* bqkv1   = (float*)(W + 110 * MB);               // 12 KB
  float* bkv2    = (float*)(W + 110 * MB + 65536);       // 8 KB
  float* y       = (float*)(W + 111 * MB); // 16 -> ends 127 MB

  // ---- converts (single segmented launch) ----
  CvtArgs ca;
  const float* srcs[14] = {x, enc, wq1, wk1, wv1, wo1, wq2, wk2, wv2, wo2, w1, w2, relk1, relk2};
  ushort* dsts[14] = {xb, encb, wqkv1b, wqkv1b + 1024 * 1024, wqkv1b + 2 * 1024 * 1024,
                      wo1b, wq2b, wkv2b, wkv2b + 1024 * 1024, wo2b, w1b, w2b, relkb1, relkb2};
  int lens[14] = {ROWS * Dm, ROWS * Dm, Dm * Dm, Dm * Dm, Dm * Dm, Dm * Dm,
                  Dm * Dm, Dm * Dm, Dm * Dm, Dm * Dm, FFd * Dm, Dm * FFd, NR * DHd, NR * DHd};
  int cum = 0;
  for (int i = 0; i < 14; i++) { ca.src[i] = srcs[i]; ca.dst[i] = dsts[i]; ca.cum[i] = cum; cum += lens[i] >> 2; }
  ca.cum[14] = cum;
  k_cvt_all<<<dim3((cum + 255) / 256), 256, 0, stream>>>(ca);
  k_bias<<<dim3(20), 256, 0, stream>>>(bq1, bk1, bv1, bk2, bv2, bqkv1, bkv2);
  k_ids8<<<dim3(2048), 256, 0, stream>>>(ids1, ids2, ids8a, ids8b);

  auto gemm = [&](int mode, int bm, const ushort* A, const ushort* Bw, const float* bias,
                  void* C, int M, int N, int K) {
    dim3 g((M / bm) * (N / 128));
    if (bm == 128) {
      if (mode == 1) k_gemm<1, 128><<<g, 256, 0, stream>>>(A, Bw, bias, C, M, N, K);
      else           k_gemm<2, 128><<<g, 256, 0, stream>>>(A, Bw, bias, C, M, N, K);
    } else {
      k_gemm<1, 64><<<g, 256, 0, stream>>>(A, Bw, bias, C, M, N, K);
    }
  };

  // ---- self attention ----
  gemm(1, 128, xb, wqkv1b, bqkv1, qkv, ROWS, 3072, Dm);
  k_flash<true><<<dim3(LQ / 64, Bn * Hh), 256, 0, stream>>>(
      qkv, qkv + 1024, qkv + 2048, relkb1, relb1, ids8a, attb, LQ, 3072, 3072);
  gemm(1, 64, attb, wo1b, bo1, t8, ROWS, 1024, Dm);
  k_addln<<<dim3(ROWS), 256, 0, stream>>>(x, t8, g1, be1, y, yb);

  // ---- cross attention ----
  gemm(1, 64, yb, wq2b, bq2, q8c, ROWS, 1024, Dm);
  gemm(1, 128, encb, wkv2b, bkv2, kv2, ROWS, 2048, Dm);
  k_flash<false><<<dim3(LQ / 64, Bn * Hh), 256, 0, stream>>>(
      q8c, kv2, kv2 + 1024, relkb2, relb2, ids8b, attb, LQ, 1024, 2048);
  gemm(1, 64, attb, wo2b, bo2, t8, ROWS, 1024, Dm);
  k_addln<<<dim3(ROWS), 256, 0, stream>>>(y, t8, g2, be2, y, yb);

  // ---- FFN ----
  gemm(2, 128, yb, w1b, b1, ffh, ROWS, FFd, Dm);
  gemm(1, 64, ffh, w2b, b2, t8, ROWS, 1024, FFd);
  k_addln<<<dim3(ROWS), 256, 0, stream>>>(y, t8, g3, be3, (float*)d_out, nullptr);
}